// Round 4
// baseline (465.161 us; speedup 1.0000x reference)
//
#include <hip/hip_runtime.h>
#include <hip/hip_bf16.h>

// DGCF forward, MI355X. f32 in/out.
// R11: bucketed CSR build. R12: all-lane k_iter epilogue + out restructure.
// R13: fuse scores/softmax/A-update/D-rowsum into k_iter.
// R14: software-pipelined 16-edge chunks (2 serial latencies/row).
// R15: ego/te tables in f32 (VALUBusy was 97% with HBM at 37% — the bf16
// unpack was half the gather VALU work; trade bandwidth for issue slots).
// bin scratch aliased into A4 (dead before A4's first write) to fund it.
#define NUSER 50000
#define NITEM 50000
#define NN    100000          // NUSER+NITEM
#define NNZ_  1000000
#define DIM_  64
#define NBLK  391             // ceil_div(NN,256) == bucket count
#define EPB   2560            // edges per bin-pass block (391*2560 >= NNZ)

#define FL_SVC    1   // svals == 0.25 (iteration 0)
#define FL_SC     2   // fused scores: dot(fn, te[tail]) -> A -> softmax -> svals, d_next
#define FL_NEXT   8   // write ego_next / te_next
#define FL_FIN    16  // out = (out + ego_row + fn) / 3
#define FL_ACONST 32  // scores: A_old == 1
#define FL_ASTORE 64  // scores: store A_new

static inline int ceil_div(int a, int b) { return (a + b - 1) / b; }

static __device__ inline float bf2f(unsigned short u) {
    return __uint_as_float(((unsigned int)u) << 16);
}
static __device__ inline unsigned short f2bf(float f) {
    unsigned int x = __float_as_uint(f);
    x += 0x7fffu + ((x >> 16) & 1u);
    return (unsigned short)(x >> 16);
}

// ego = concat(user,item) f32; te = tanh(l2norm chunk16) f32; out = ego f32.
__global__ void k_init(const float* __restrict__ eu, const float* __restrict__ ei,
                       float* __restrict__ ego, float* __restrict__ te,
                       float* __restrict__ out) {
    int i = blockIdx.x * 256 + threadIdx.x;
    if (i >= NN * DIM_) return;
    float v = (i < NUSER * DIM_) ? eu[i] : ei[i - NUSER * DIM_];
    out[i] = v;
    ego[i] = v;
    float s = v * v;
    s += __shfl_xor(s, 1); s += __shfl_xor(s, 2);
    s += __shfl_xor(s, 4); s += __shfl_xor(s, 8);
    float nrm = v / fmaxf(sqrtf(s), 1e-12f);
    float ex = __expf(2.0f * nrm);
    te[i] = (ex - 1.0f) / (ex + 1.0f);
}

// ---- bucketed CSR build (once per launch) ----
__global__ void k_bcount(const int* __restrict__ head, int* __restrict__ bcount) {
    __shared__ int cnt[NBLK];
    int tid = threadIdx.x;
    for (int i = tid; i < NBLK; i += 256) cnt[i] = 0;
    __syncthreads();
    int e0 = blockIdx.x * EPB;
    int e1 = min(e0 + EPB, NNZ_);
    for (int e = e0 + tid; e < e1; e += 256)
        atomicAdd(&cnt[head[e] >> 8], 1);
    __syncthreads();
    for (int i = tid; i < NBLK; i += 256)
        if (cnt[i]) atomicAdd(&bcount[i], cnt[i]);
}

__global__ void k_bscan(const int* __restrict__ bcount, int* __restrict__ bucket_base,
                        int* __restrict__ bucket_cursor, int* __restrict__ row_start_end) {
    __shared__ int sh[512];
    int t = threadIdx.x;
    int v = (t < NBLK) ? bcount[t] : 0;
    sh[t] = v;
    __syncthreads();
    for (int off = 1; off < 512; off <<= 1) {
        int u = 0;
        if (t >= off) u = sh[t - off];
        __syncthreads();
        sh[t] += u;
        __syncthreads();
    }
    if (t < NBLK) {
        int base = sh[t] - v;
        bucket_base[t] = base;
        bucket_cursor[t] = base;
    }
    if (t == 511) {
        bucket_base[NBLK] = sh[511];    // == NNZ_
        row_start_end[0] = sh[511];
    }
}

__global__ void k_binscat(const int* __restrict__ head, const int* __restrict__ tail,
                          int* __restrict__ bucket_cursor, int2* __restrict__ bin) {
    __shared__ int cnt[NBLK];
    __shared__ int chunk[NBLK];
    int tid = threadIdx.x;
    for (int i = tid; i < NBLK; i += 256) cnt[i] = 0;
    __syncthreads();
    int e0 = blockIdx.x * EPB;
    int e1 = min(e0 + EPB, NNZ_);
    for (int e = e0 + tid; e < e1; e += 256)
        atomicAdd(&cnt[head[e] >> 8], 1);
    __syncthreads();
    for (int i = tid; i < NBLK; i += 256) {
        chunk[i] = cnt[i] ? atomicAdd(&bucket_cursor[i], cnt[i]) : 0;
        cnt[i] = 0;   // reuse as local cursor
    }
    __syncthreads();
    for (int e = e0 + tid; e < e1; e += 256) {
        int h = head[e], t = tail[e];
        int b = h >> 8;
        int off = atomicAdd(&cnt[b], 1);
        bin[chunk[b] + off] = make_int2(h, t);
    }
}

__global__ void k_bucket(const int2* __restrict__ bin, const int* __restrict__ bucket_base,
                         int* __restrict__ row_start, float4* __restrict__ d4a,
                         int* __restrict__ csr_tail) {
    __shared__ int deg[256];
    __shared__ int sh[256];
    __shared__ int cur[256];
    int tid = threadIdx.x;
    int b = blockIdx.x;
    int n0 = b << 8;
    int e0 = bucket_base[b], e1 = bucket_base[b + 1];
    deg[tid] = 0;
    __syncthreads();
    for (int e = e0 + tid; e < e1; e += 256)
        atomicAdd(&deg[bin[e].x - n0], 1);
    __syncthreads();
    int myDeg = deg[tid];
    sh[tid] = myDeg;
    __syncthreads();
    for (int off = 1; off < 256; off <<= 1) {
        int u = 0;
        if (tid >= off) u = sh[tid - off];
        __syncthreads();
        sh[tid] += u;
        __syncthreads();
    }
    int loff = sh[tid] - myDeg;   // exclusive local offset
    int n = n0 + tid;
    if (n < NN) {
        row_start[n] = e0 + loff;
        float dd = (myDeg > 0) ? 2.0f / sqrtf((float)myDeg) : 0.0f;
        d4a[n] = make_float4(dd, dd, dd, dd);
    }
    cur[tid] = e0 + loff;
    __syncthreads();
    for (int e = e0 + tid; e < e1; e += 256) {
        int2 p = bin[e];
        int pos = atomicAdd(&cur[p.x - n0], 1);
        csr_tail[pos] = p.y;
    }
}

// ---- fused walk + scores, pipelined: one wave per node ----
// lane = 16*q + l: q = edge slot (0..3), l = dim quad (dims 4l..4l+3), f = l>>2.
// chunk0 (edges r0..r0+16): level0 loads (tail/sval/A4) -> level1 gathers
// (d4/ego/te, f32 float4) -> register compute; te cached for the scores phase.
// deg>16: same 16-wide pipelined chunks in a loop (te re-gathered in phase 2).
template<int FLAGS>
__global__ void k_iter(unsigned short* __restrict__ svals,  // bf16 [NNZ*4] gather-in / scores-out
                       const float* __restrict__ d4c,       // f32 [NN*4]
                       const float* __restrict__ ego,       // f32 [NN*64]
                       const float* __restrict__ te,        // f32 [NN*64]
                       const int* __restrict__ row_start, const int* __restrict__ csr_tail,
                       float* __restrict__ A4,              // f32 [NNZ*4]
                       float* __restrict__ d4n,             // f32 [NN*4]
                       float* __restrict__ out,
                       float* __restrict__ egon, float* __restrict__ ten) {
    int n = (blockIdx.x * 256 + threadIdx.x) >> 6;
    if (n >= NN) return;
    int lane = threadIdx.x & 63;
    int q = lane >> 4;
    int l = lane & 15;
    int f = l >> 2;
    int r0 = __builtin_amdgcn_readfirstlane(row_start[n]);
    int r1 = __builtin_amdgcn_readfirstlane(row_start[n + 1]);

    float ax = 0.f, ay = 0.f, az = 0.f, aw = 0.f;

    // ---- chunk 0: edges r0+q+4j, j=0..3 (te cached for scores phase) ----
    int ct[4]; float cw[4]; float ca[4]; float4 cv[4]; float cd[4];
    int eb = r0 + q;
    // level 0: independent loads, issued back-to-back
#pragma unroll
    for (int j = 0; j < 4; ++j) {
        int i = eb + 4 * j;
        bool v = (i < r1);
        int ic = v ? i : 0;
        ct[j] = csr_tail[ic];
        float w;
        if (FLAGS & FL_SVC) w = 0.25f;
        else w = bf2f(svals[(size_t)ic * 4 + f]);
        cw[j] = v ? w : 0.f;
        if ((FLAGS & FL_SC) && !(FLAGS & FL_ACONST))
            ca[j] = A4[(size_t)ic * 4 + f];
    }
    // level 1: gathers depending only on tails, issued back-to-back
#pragma unroll
    for (int j = 0; j < 4; ++j) {
        int t = ct[j];
        cd[j] = d4c[t * 4 + f];
        if (FLAGS & FL_SC)
            cv[j] = *(const float4*)(te + (size_t)t * 64 + 4 * l);
    }
#pragma unroll
    for (int j = 0; j < 4; ++j) {
        int t = ct[j];
        float4 u = *(const float4*)(ego + (size_t)t * 64 + 4 * l);
        float w = cw[j] * cd[j];
        ax += w * u.x; ay += w * u.y;
        az += w * u.z; aw += w * u.w;
    }

    // ---- remainder chunks (deg > 16), same pipeline, not cached ----
    for (int base = r0 + 16; base < r1; base += 16) {
        int tj[4]; float wj[4];
#pragma unroll
        for (int j = 0; j < 4; ++j) {
            int i = base + q + 4 * j;
            bool v = (i < r1);
            int ic = v ? i : 0;
            tj[j] = csr_tail[ic];
            float w;
            if (FLAGS & FL_SVC) w = 0.25f;
            else w = bf2f(svals[(size_t)ic * 4 + f]);
            wj[j] = v ? w : 0.f;
        }
#pragma unroll
        for (int j = 0; j < 4; ++j) {
            int t = tj[j];
            float w = wj[j] * d4c[t * 4 + f];
            float4 u = *(const float4*)(ego + (size_t)t * 64 + 4 * l);
            ax += w * u.x; ay += w * u.y;
            az += w * u.z; aw += w * u.w;
        }
    }

    // reduce over edge slots -> each lane holds full sums for its dim quad
    ax += __shfl_xor(ax, 16); ax += __shfl_xor(ax, 32);
    ay += __shfl_xor(ay, 16); ay += __shfl_xor(ay, 32);
    az += __shfl_xor(az, 16); az += __shfl_xor(az, 32);
    aw += __shfl_xor(aw, 16); aw += __shfl_xor(aw, 32);

    // l2 norm over the 16-dim factor chunk (quad layout: reduce over l&3)
    float s = ax * ax + ay * ay + az * az + aw * aw;
    s += __shfl_xor(s, 1); s += __shfl_xor(s, 2);
    float inv = 1.0f / fmaxf(sqrtf(s), 1e-12f);
    float fx = ax * inv, fy = ay * inv, fz = az * inv, fw = aw * inv;

    if (FLAGS & (FL_NEXT | FL_FIN)) {
        // redistribute: lane p takes dim p (= component p&3 of lane p>>2's quad)
        int src = lane >> 2;
        float t0r = __shfl(fx, src), t1r = __shfl(fy, src);
        float t2r = __shfl(fz, src), t3r = __shfl(fw, src);
        float y = (lane & 2) ? ((lane & 1) ? t3r : t2r) : ((lane & 1) ? t1r : t0r);
        size_t base = (size_t)n * 64 + lane;
        if (FLAGS & FL_FIN) {
            // out holds init; walk table row n holds f32 fn1 -> 3-term mean
            out[base] = (out[base] + ego[base] + y) * (1.0f / 3.0f);
        }
        if (FLAGS & FL_NEXT) {
            egon[base] = y;
            float e2 = __expf(2.0f * y);
            ten[base] = (e2 - 1.0f) / (e2 + 1.0f);
        }
    }

    if (FLAGS & FL_SC) {
        float accs = 0.f;   // rowsum of svals for this lane's factor f
        // cached chunk 0: pure register compute
#pragma unroll
        for (int j = 0; j < 4; ++j) {
            int i = eb + 4 * j;
            bool v = (i < r1);
            float4 u = cv[j];
            float dot = fx * u.x + fy * u.y + fz * u.z + fw * u.w;
            dot += __shfl_xor(dot, 1); dot += __shfl_xor(dot, 2);
            float a = (FLAGS & FL_ACONST) ? 1.0f : ca[j];
            a += dot;
            if ((FLAGS & FL_ASTORE) && v && (l & 3) == 0)
                A4[(size_t)i * 4 + f] = a;
            float ex = __expf(a);
            float sum = ex;
            sum += __shfl_xor(sum, 4); sum += __shfl_xor(sum, 8);
            float sv = ex / sum;
            if (v && (l & 3) == 0)
                svals[(size_t)i * 4 + f] = f2bf(sv);
            accs += v ? sv : 0.f;
        }
        // remainder chunks: pipelined re-gather of tails/A4 -> te
        for (int base = r0 + 16; base < r1; base += 16) {
            int tj[4]; float aj[4]; float4 vj[4];
#pragma unroll
            for (int j = 0; j < 4; ++j) {
                int i = base + q + 4 * j;
                bool v = (i < r1);
                int ic = v ? i : 0;
                tj[j] = csr_tail[ic];
                if (!(FLAGS & FL_ACONST)) aj[j] = A4[(size_t)ic * 4 + f];
            }
#pragma unroll
            for (int j = 0; j < 4; ++j)
                vj[j] = *(const float4*)(te + (size_t)tj[j] * 64 + 4 * l);
#pragma unroll
            for (int j = 0; j < 4; ++j) {
                int i = base + q + 4 * j;
                bool v = (i < r1);
                float4 u = vj[j];
                float dot = fx * u.x + fy * u.y + fz * u.z + fw * u.w;
                dot += __shfl_xor(dot, 1); dot += __shfl_xor(dot, 2);
                float a = (FLAGS & FL_ACONST) ? 1.0f : aj[j];
                a += dot;
                if ((FLAGS & FL_ASTORE) && v && (l & 3) == 0)
                    A4[(size_t)i * 4 + f] = a;
                float ex = __expf(a);
                float sum = ex;
                sum += __shfl_xor(sum, 4); sum += __shfl_xor(sum, 8);
                float sv = ex / sum;
                if (v && (l & 3) == 0)
                    svals[(size_t)i * 4 + f] = f2bf(sv);
                accs += v ? sv : 0.f;
            }
        }
        // reduce over edge slots q (value replicated over the l&3 dups)
        accs += __shfl_xor(accs, 16); accs += __shfl_xor(accs, 32);
        if (lane < 16 && (l & 3) == 0) {
            float d = (accs > 0.f) ? 1.0f / sqrtf(fmaxf(accs, 1e-12f)) : 0.f;
            d4n[(size_t)n * 4 + f] = d;
        }
    }
}

extern "C" void kernel_launch(void* const* d_in, const int* in_sizes, int n_in,
                              void* d_out, int out_size, void* d_ws, size_t ws_size,
                              hipStream_t stream) {
    const float* eu = (const float*)d_in[0];
    const float* ei = (const float*)d_in[1];
    const int* head = (const int*)d_in[2];
    const int* tail = (const int*)d_in[3];
    float* out = (float*)d_out;   // holds init until it3's 3-term mean (FL_FIN)

    // workspace layout — ~134 MB (16B-aligned first).
    // bin (8 MB, CSR-build scratch) aliases A4's first half: bin is dead after
    // k_bucket; A4 is first written in it0 (same stream => ordered).
    float* A4 = (float*)d_ws;                               // 16 MB
    float* d4a = A4 + (size_t)NNZ_ * 4;                     // 1.6 MB
    float* d4b = d4a + (size_t)NN * 4;                      // 1.6 MB
    unsigned short* svals = (unsigned short*)(d4b + (size_t)NN * 4);  // 8 MB
    float* ego_a = (float*)(svals + (size_t)NNZ_ * 4);      // 25.6 MB
    float* te_a  = ego_a + (size_t)NN * DIM_;               // 25.6 MB
    float* ego_b = te_a + (size_t)NN * DIM_;                // 25.6 MB
    float* te_b  = ego_b + (size_t)NN * DIM_;               // 25.6 MB
    int* csr_tail = (int*)(te_b + (size_t)NN * DIM_);       // 4 MB
    int* row_start = csr_tail + NNZ_;                       // NN+1
    int* bcount = row_start + (NN + 1);                     // NBLK
    int* bucket_base = bcount + NBLK;                       // NBLK+1
    int* bucket_cursor = bucket_base + (NBLK + 1);          // NBLK
    int2* bin = (int2*)A4;                                  // 8 MB alias

    const int node_blocks = ceil_div(NN * DIM_, 256);      // 25000
    const int wave_blocks = ceil_div(NN * 64, 256);        // 25000

    k_init<<<node_blocks, 256, 0, stream>>>(eu, ei, ego_a, te_a, out);

    // bucketed CSR build + d4_0 seed (d = 2/sqrt(deg) since svals_0 = 0.25)
    hipMemsetAsync(bcount, 0, NBLK * sizeof(int), stream);
    k_bcount<<<NBLK, 256, 0, stream>>>(head, bcount);
    k_bscan<<<1, 512, 0, stream>>>(bcount, bucket_base, bucket_cursor, &row_start[NN]);
    k_binscat<<<NBLK, 256, 0, stream>>>(head, tail, bucket_cursor, bin);
    k_bucket<<<NBLK, 256, 0, stream>>>(bin, bucket_base, row_start, (float4*)d4a, csr_tail);

    // it0 = (0,0): gather with svals==0.25; scores vs te_a: A1 = 1 + s0 (store),
    // svals_1 = softmax(A1), d4b = D(svals_1).
    k_iter<FL_SVC | FL_SC | FL_ACONST | FL_ASTORE><<<wave_blocks, 256, 0, stream>>>(
        svals, d4a, ego_a, te_a, row_start, csr_tail, A4, d4b, out, ego_b, te_b);

    // it1 = (0,1): layer-0 output -> ego_b/te_b (FL_NEXT); scores vs te_a:
    // A2 = A1 + s1 (store), svals_2, d4a.
    k_iter<FL_SC | FL_ASTORE | FL_NEXT><<<wave_blocks, 256, 0, stream>>>(
        svals, d4b, ego_a, te_a, row_start, csr_tail, A4, d4a, out, ego_b, te_b);

    // it2 = (1,0): gather ego_b; scores vs te_b: A3 = A2 + s2 (A3 store dead),
    // svals_3, d4b. No fn store needed at all.
    k_iter<FL_SC><<<wave_blocks, 256, 0, stream>>>(
        svals, d4a, ego_b, te_b, row_start, csr_tail, A4, d4b, out, ego_b, te_b);

    // it3 = (1,1): no scores; final out = (init + fn1(f32 via ego_b) + fn3) / 3.
    k_iter<FL_FIN><<<wave_blocks, 256, 0, stream>>>(
        svals, d4b, ego_b, te_b, row_start, csr_tail, A4, d4a, out, ego_b, te_b);
}

// Round 5
// 352.227 us; speedup vs baseline: 1.3206x; 1.3206x over previous
//
#include <hip/hip_runtime.h>
#include <hip/hip_bf16.h>

// DGCF forward, MI355X. f32 in/out.
// R11: bucketed CSR build. R12: all-lane k_iter epilogue + out restructure.
// R13: fuse scores/softmax/A-update/D-rowsum into k_iter.
// R14: software-pipelined 16-edge chunks (2 serial latencies/row).
// R15 (reverted): f32 tables doubled FETCH, random-gather path can't stream.
// R16: bf16 tables again + (a) wave-uniform degree-adaptive chunk depth
// (iter_body<NJ=1..4> picked by scalar branch on deg — kills the ~37% of
// issue slots wasted on invalid edge slots at avg deg 10) and (b) 32-bit
// indices everywhere (no size_t chains -> saddr-form addressing).
#define NUSER 50000
#define NITEM 50000
#define NN    100000          // NUSER+NITEM
#define NNZ_  1000000
#define DIM_  64
#define NBLK  391             // ceil_div(NN,256) == bucket count
#define EPB   2560            // edges per bin-pass block (391*2560 >= NNZ)

#define FL_SVC    1   // svals == 0.25 (iteration 0)
#define FL_SC     2   // fused scores: dot(fn, te[tail]) -> A -> softmax -> svals, d_next
#define FL_NEXT   8   // write ego_next / te_next
#define FL_FIN    16  // out = (out + ego_row + fn) / 3
#define FL_ACONST 32  // scores: A_old == 1
#define FL_ASTORE 64  // scores: store A_new

static inline int ceil_div(int a, int b) { return (a + b - 1) / b; }

static __device__ inline float bf2f(unsigned short u) {
    return __uint_as_float(((unsigned int)u) << 16);
}
static __device__ inline unsigned short f2bf(float f) {
    unsigned int x = __float_as_uint(f);
    x += 0x7fffu + ((x >> 16) & 1u);
    return (unsigned short)(x >> 16);
}

// ego = concat(user,item) bf16; te = tanh(l2norm chunk16) bf16; out = ego f32.
__global__ void k_init(const float* __restrict__ eu, const float* __restrict__ ei,
                       unsigned short* __restrict__ ego, unsigned short* __restrict__ te,
                       float* __restrict__ out) {
    int i = blockIdx.x * 256 + threadIdx.x;
    if (i >= NN * DIM_) return;
    float v = (i < NUSER * DIM_) ? eu[i] : ei[i - NUSER * DIM_];
    out[i] = v;
    ego[i] = f2bf(v);
    float s = v * v;
    s += __shfl_xor(s, 1); s += __shfl_xor(s, 2);
    s += __shfl_xor(s, 4); s += __shfl_xor(s, 8);
    float nrm = v / fmaxf(sqrtf(s), 1e-12f);
    float ex = __expf(2.0f * nrm);
    te[i] = f2bf((ex - 1.0f) / (ex + 1.0f));
}

// ---- bucketed CSR build (once per launch) ----
__global__ void k_bcount(const int* __restrict__ head, int* __restrict__ bcount) {
    __shared__ int cnt[NBLK];
    int tid = threadIdx.x;
    for (int i = tid; i < NBLK; i += 256) cnt[i] = 0;
    __syncthreads();
    int e0 = blockIdx.x * EPB;
    int e1 = min(e0 + EPB, NNZ_);
    for (int e = e0 + tid; e < e1; e += 256)
        atomicAdd(&cnt[head[e] >> 8], 1);
    __syncthreads();
    for (int i = tid; i < NBLK; i += 256)
        if (cnt[i]) atomicAdd(&bcount[i], cnt[i]);
}

__global__ void k_bscan(const int* __restrict__ bcount, int* __restrict__ bucket_base,
                        int* __restrict__ bucket_cursor, int* __restrict__ row_start_end) {
    __shared__ int sh[512];
    int t = threadIdx.x;
    int v = (t < NBLK) ? bcount[t] : 0;
    sh[t] = v;
    __syncthreads();
    for (int off = 1; off < 512; off <<= 1) {
        int u = 0;
        if (t >= off) u = sh[t - off];
        __syncthreads();
        sh[t] += u;
        __syncthreads();
    }
    if (t < NBLK) {
        int base = sh[t] - v;
        bucket_base[t] = base;
        bucket_cursor[t] = base;
    }
    if (t == 511) {
        bucket_base[NBLK] = sh[511];    // == NNZ_
        row_start_end[0] = sh[511];
    }
}

__global__ void k_binscat(const int* __restrict__ head, const int* __restrict__ tail,
                          int* __restrict__ bucket_cursor, int2* __restrict__ bin) {
    __shared__ int cnt[NBLK];
    __shared__ int chunk[NBLK];
    int tid = threadIdx.x;
    for (int i = tid; i < NBLK; i += 256) cnt[i] = 0;
    __syncthreads();
    int e0 = blockIdx.x * EPB;
    int e1 = min(e0 + EPB, NNZ_);
    for (int e = e0 + tid; e < e1; e += 256)
        atomicAdd(&cnt[head[e] >> 8], 1);
    __syncthreads();
    for (int i = tid; i < NBLK; i += 256) {
        chunk[i] = cnt[i] ? atomicAdd(&bucket_cursor[i], cnt[i]) : 0;
        cnt[i] = 0;   // reuse as local cursor
    }
    __syncthreads();
    for (int e = e0 + tid; e < e1; e += 256) {
        int h = head[e], t = tail[e];
        int b = h >> 8;
        int off = atomicAdd(&cnt[b], 1);
        bin[chunk[b] + off] = make_int2(h, t);
    }
}

__global__ void k_bucket(const int2* __restrict__ bin, const int* __restrict__ bucket_base,
                         int* __restrict__ row_start, float4* __restrict__ d4a,
                         int* __restrict__ csr_tail) {
    __shared__ int deg[256];
    __shared__ int sh[256];
    __shared__ int cur[256];
    int tid = threadIdx.x;
    int b = blockIdx.x;
    int n0 = b << 8;
    int e0 = bucket_base[b], e1 = bucket_base[b + 1];
    deg[tid] = 0;
    __syncthreads();
    for (int e = e0 + tid; e < e1; e += 256)
        atomicAdd(&deg[bin[e].x - n0], 1);
    __syncthreads();
    int myDeg = deg[tid];
    sh[tid] = myDeg;
    __syncthreads();
    for (int off = 1; off < 256; off <<= 1) {
        int u = 0;
        if (tid >= off) u = sh[tid - off];
        __syncthreads();
        sh[tid] += u;
        __syncthreads();
    }
    int loff = sh[tid] - myDeg;   // exclusive local offset
    int n = n0 + tid;
    if (n < NN) {
        row_start[n] = e0 + loff;
        float dd = (myDeg > 0) ? 2.0f / sqrtf((float)myDeg) : 0.0f;
        d4a[n] = make_float4(dd, dd, dd, dd);
    }
    cur[tid] = e0 + loff;
    __syncthreads();
    for (int e = e0 + tid; e < e1; e += 256) {
        int2 p = bin[e];
        int pos = atomicAdd(&cur[p.x - n0], 1);
        csr_tail[pos] = p.y;
    }
}

// ---- fused walk + scores body, NJ = chunk depth in 4-edge steps ----
// lane = 16*q + l: q = edge slot (0..3), l = dim quad (dims 4l..4l+3), f = l>>2.
// All indices 32-bit (max byte offset 12.8 MB << 2^31).
template<int FLAGS, int NJ>
static __device__ __forceinline__ void iter_body(
    int n, int lane, int q, int l, int f, int r0, int r1,
    unsigned short* __restrict__ svals, const float* __restrict__ d4c,
    const unsigned short* __restrict__ ego, const unsigned short* __restrict__ te,
    const int* __restrict__ csr_tail,
    float* __restrict__ A4, float* __restrict__ d4n,
    float* __restrict__ out,
    unsigned short* __restrict__ egon, unsigned short* __restrict__ ten)
{
    float ax = 0.f, ay = 0.f, az = 0.f, aw = 0.f;

    // ---- chunk 0: edges r0+q+4j, j=0..NJ-1 (te cached for scores phase) ----
    int ct[NJ]; float cw[NJ]; float ca[NJ]; ushort4 cv[NJ]; float cd[NJ];
    int eb = r0 + q;
    // level 0: independent loads, issued back-to-back
#pragma unroll
    for (int j = 0; j < NJ; ++j) {
        int i = eb + 4 * j;
        bool v = (i < r1);
        int ic = v ? i : 0;
        ct[j] = csr_tail[ic];
        float w;
        if (FLAGS & FL_SVC) w = 0.25f;
        else w = bf2f(svals[ic * 4 + f]);
        cw[j] = v ? w : 0.f;
        if ((FLAGS & FL_SC) && !(FLAGS & FL_ACONST))
            ca[j] = A4[ic * 4 + f];
    }
    // level 1: gathers depending only on tails, issued back-to-back
#pragma unroll
    for (int j = 0; j < NJ; ++j) {
        int t = ct[j];
        cd[j] = d4c[t * 4 + f];
        if (FLAGS & FL_SC)
            cv[j] = *(const ushort4*)(te + t * 64 + 4 * l);
    }
#pragma unroll
    for (int j = 0; j < NJ; ++j) {
        ushort4 u = *(const ushort4*)(ego + ct[j] * 64 + 4 * l);
        float w = cw[j] * cd[j];
        ax += w * bf2f(u.x); ay += w * bf2f(u.y);
        az += w * bf2f(u.z); aw += w * bf2f(u.w);
    }

    // ---- remainder chunks (deg > 16), only reachable in the NJ==4 arm ----
    if (NJ == 4) {
        for (int base = r0 + 16; base < r1; base += 16) {
            int tj[4]; float wj[4];
#pragma unroll
            for (int j = 0; j < 4; ++j) {
                int i = base + q + 4 * j;
                bool v = (i < r1);
                int ic = v ? i : 0;
                tj[j] = csr_tail[ic];
                float w;
                if (FLAGS & FL_SVC) w = 0.25f;
                else w = bf2f(svals[ic * 4 + f]);
                wj[j] = v ? w : 0.f;
            }
#pragma unroll
            for (int j = 0; j < 4; ++j) {
                int t = tj[j];
                float w = wj[j] * d4c[t * 4 + f];
                ushort4 u = *(const ushort4*)(ego + t * 64 + 4 * l);
                ax += w * bf2f(u.x); ay += w * bf2f(u.y);
                az += w * bf2f(u.z); aw += w * bf2f(u.w);
            }
        }
    }

    // reduce over edge slots -> each lane holds full sums for its dim quad
    ax += __shfl_xor(ax, 16); ax += __shfl_xor(ax, 32);
    ay += __shfl_xor(ay, 16); ay += __shfl_xor(ay, 32);
    az += __shfl_xor(az, 16); az += __shfl_xor(az, 32);
    aw += __shfl_xor(aw, 16); aw += __shfl_xor(aw, 32);

    // l2 norm over the 16-dim factor chunk (quad layout: reduce over l&3)
    float s = ax * ax + ay * ay + az * az + aw * aw;
    s += __shfl_xor(s, 1); s += __shfl_xor(s, 2);
    float inv = 1.0f / fmaxf(sqrtf(s), 1e-12f);
    float fx = ax * inv, fy = ay * inv, fz = az * inv, fw = aw * inv;

    if (FLAGS & (FL_NEXT | FL_FIN)) {
        // redistribute: lane p takes dim p (= component p&3 of lane p>>2's quad)
        int src = lane >> 2;
        float t0r = __shfl(fx, src), t1r = __shfl(fy, src);
        float t2r = __shfl(fz, src), t3r = __shfl(fw, src);
        float y = (lane & 2) ? ((lane & 1) ? t3r : t2r) : ((lane & 1) ? t1r : t0r);
        int base = n * 64 + lane;
        if (FLAGS & FL_FIN) {
            // out holds init; walk table row n holds bf16 fn1 -> 3-term mean
            out[base] = (out[base] + bf2f(ego[base]) + y) * (1.0f / 3.0f);
        }
        if (FLAGS & FL_NEXT) {
            egon[base] = f2bf(y);
            float e2 = __expf(2.0f * y);
            ten[base] = f2bf((e2 - 1.0f) / (e2 + 1.0f));
        }
    }

    if (FLAGS & FL_SC) {
        float accs = 0.f;   // rowsum of svals for this lane's factor f
        // cached chunk 0: pure register compute
#pragma unroll
        for (int j = 0; j < NJ; ++j) {
            int i = eb + 4 * j;
            bool v = (i < r1);
            ushort4 u = cv[j];
            float dot = fx * bf2f(u.x) + fy * bf2f(u.y)
                      + fz * bf2f(u.z) + fw * bf2f(u.w);
            dot += __shfl_xor(dot, 1); dot += __shfl_xor(dot, 2);
            float a = (FLAGS & FL_ACONST) ? 1.0f : ca[j];
            a += dot;
            if ((FLAGS & FL_ASTORE) && v && (l & 3) == 0)
                A4[i * 4 + f] = a;
            float ex = __expf(a);
            float sum = ex;
            sum += __shfl_xor(sum, 4); sum += __shfl_xor(sum, 8);
            float sv = ex / sum;
            if (v && (l & 3) == 0)
                svals[i * 4 + f] = f2bf(sv);
            accs += v ? sv : 0.f;
        }
        // remainder chunks: pipelined re-gather of tails/A4 -> te
        if (NJ == 4) {
            for (int base = r0 + 16; base < r1; base += 16) {
                int tj[4]; float aj[4]; ushort4 vj[4];
#pragma unroll
                for (int j = 0; j < 4; ++j) {
                    int i = base + q + 4 * j;
                    bool v = (i < r1);
                    int ic = v ? i : 0;
                    tj[j] = csr_tail[ic];
                    if (!(FLAGS & FL_ACONST)) aj[j] = A4[ic * 4 + f];
                }
#pragma unroll
                for (int j = 0; j < 4; ++j)
                    vj[j] = *(const ushort4*)(te + tj[j] * 64 + 4 * l);
#pragma unroll
                for (int j = 0; j < 4; ++j) {
                    int i = base + q + 4 * j;
                    bool v = (i < r1);
                    ushort4 u = vj[j];
                    float dot = fx * bf2f(u.x) + fy * bf2f(u.y)
                              + fz * bf2f(u.z) + fw * bf2f(u.w);
                    dot += __shfl_xor(dot, 1); dot += __shfl_xor(dot, 2);
                    float a = (FLAGS & FL_ACONST) ? 1.0f : aj[j];
                    a += dot;
                    if ((FLAGS & FL_ASTORE) && v && (l & 3) == 0)
                        A4[i * 4 + f] = a;
                    float ex = __expf(a);
                    float sum = ex;
                    sum += __shfl_xor(sum, 4); sum += __shfl_xor(sum, 8);
                    float sv = ex / sum;
                    if (v && (l & 3) == 0)
                        svals[i * 4 + f] = f2bf(sv);
                    accs += v ? sv : 0.f;
                }
            }
        }
        // reduce over edge slots q (value replicated over the l&3 dups)
        accs += __shfl_xor(accs, 16); accs += __shfl_xor(accs, 32);
        if (lane < 16 && (l & 3) == 0) {
            float d = (accs > 0.f) ? 1.0f / sqrtf(fmaxf(accs, 1e-12f)) : 0.f;
            d4n[n * 4 + f] = d;
        }
    }
}

// dispatcher: one wave per node; deg is wave-uniform (SGPR) -> scalar branch
template<int FLAGS>
__global__ void k_iter(unsigned short* __restrict__ svals,
                       const float* __restrict__ d4c,
                       const unsigned short* __restrict__ ego,
                       const unsigned short* __restrict__ te,
                       const int* __restrict__ row_start, const int* __restrict__ csr_tail,
                       float* __restrict__ A4,
                       float* __restrict__ d4n,
                       float* __restrict__ out,
                       unsigned short* __restrict__ egon, unsigned short* __restrict__ ten) {
    int n = (blockIdx.x * 256 + threadIdx.x) >> 6;
    if (n >= NN) return;
    int lane = threadIdx.x & 63;
    int q = lane >> 4;
    int l = lane & 15;
    int f = l >> 2;
    int r0 = __builtin_amdgcn_readfirstlane(row_start[n]);
    int r1 = __builtin_amdgcn_readfirstlane(row_start[n + 1]);
    int deg = r1 - r0;
    if (deg <= 8) {
        if (deg <= 4)
            iter_body<FLAGS, 1>(n, lane, q, l, f, r0, r1, svals, d4c, ego, te,
                                csr_tail, A4, d4n, out, egon, ten);
        else
            iter_body<FLAGS, 2>(n, lane, q, l, f, r0, r1, svals, d4c, ego, te,
                                csr_tail, A4, d4n, out, egon, ten);
    } else {
        if (deg <= 12)
            iter_body<FLAGS, 3>(n, lane, q, l, f, r0, r1, svals, d4c, ego, te,
                                csr_tail, A4, d4n, out, egon, ten);
        else
            iter_body<FLAGS, 4>(n, lane, q, l, f, r0, r1, svals, d4c, ego, te,
                                csr_tail, A4, d4n, out, egon, ten);
    }
}

extern "C" void kernel_launch(void* const* d_in, const int* in_sizes, int n_in,
                              void* d_out, int out_size, void* d_ws, size_t ws_size,
                              hipStream_t stream) {
    const float* eu = (const float*)d_in[0];
    const float* ei = (const float*)d_in[1];
    const int* head = (const int*)d_in[2];
    const int* tail = (const int*)d_in[3];
    float* out = (float*)d_out;   // holds init until it3's 3-term mean (FL_FIN)

    // workspace layout — ~87 MB (16B-aligned first).
    // bin (8 MB, CSR-build scratch) aliases A4's first half: bin is dead after
    // k_bucket; A4 is first written in it0 (same stream => ordered).
    float* A4 = (float*)d_ws;                               // 16 MB
    float* d4a = A4 + (size_t)NNZ_ * 4;                     // 1.6 MB
    float* d4b = d4a + (size_t)NN * 4;                      // 1.6 MB
    unsigned short* svals = (unsigned short*)(d4b + (size_t)NN * 4);  // 8 MB
    unsigned short* ego_a = svals + (size_t)NNZ_ * 4;       // 12.8 MB
    unsigned short* te_a  = ego_a + (size_t)NN * DIM_;      // 12.8 MB
    unsigned short* ego_b = te_a + (size_t)NN * DIM_;       // 12.8 MB
    unsigned short* te_b  = ego_b + (size_t)NN * DIM_;      // 12.8 MB
    int* csr_tail = (int*)(te_b + (size_t)NN * DIM_);       // 4 MB
    int* row_start = csr_tail + NNZ_;                       // NN+1
    int* bcount = row_start + (NN + 1);                     // NBLK
    int* bucket_base = bcount + NBLK;                       // NBLK+1
    int* bucket_cursor = bucket_base + (NBLK + 1);          // NBLK
    int2* bin = (int2*)A4;                                  // 8 MB alias

    const int node_blocks = ceil_div(NN * DIM_, 256);      // 25000
    const int wave_blocks = ceil_div(NN * 64, 256);        // 25000

    k_init<<<node_blocks, 256, 0, stream>>>(eu, ei, ego_a, te_a, out);

    // bucketed CSR build + d4_0 seed (d = 2/sqrt(deg) since svals_0 = 0.25)
    hipMemsetAsync(bcount, 0, NBLK * sizeof(int), stream);
    k_bcount<<<NBLK, 256, 0, stream>>>(head, bcount);
    k_bscan<<<1, 512, 0, stream>>>(bcount, bucket_base, bucket_cursor, &row_start[NN]);
    k_binscat<<<NBLK, 256, 0, stream>>>(head, tail, bucket_cursor, bin);
    k_bucket<<<NBLK, 256, 0, stream>>>(bin, bucket_base, row_start, (float4*)d4a, csr_tail);

    // it0 = (0,0): gather with svals==0.25; scores vs te_a: A1 = 1 + s0 (store),
    // svals_1 = softmax(A1), d4b = D(svals_1).
    k_iter<FL_SVC | FL_SC | FL_ACONST | FL_ASTORE><<<wave_blocks, 256, 0, stream>>>(
        svals, d4a, ego_a, te_a, row_start, csr_tail, A4, d4b, out, ego_b, te_b);

    // it1 = (0,1): layer-0 output -> ego_b/te_b (FL_NEXT); scores vs te_a:
    // A2 = A1 + s1 (store), svals_2, d4a.
    k_iter<FL_SC | FL_ASTORE | FL_NEXT><<<wave_blocks, 256, 0, stream>>>(
        svals, d4b, ego_a, te_a, row_start, csr_tail, A4, d4a, out, ego_b, te_b);

    // it2 = (1,0): gather ego_b; scores vs te_b: A3 = A2 + s2 (A3 store dead),
    // svals_3, d4b. No fn store needed at all.
    k_iter<FL_SC><<<wave_blocks, 256, 0, stream>>>(
        svals, d4a, ego_b, te_b, row_start, csr_tail, A4, d4b, out, ego_b, te_b);

    // it3 = (1,1): no scores; final out = (init + fn1(bf16 via ego_b) + fn3) / 3.
    k_iter<FL_FIN><<<wave_blocks, 256, 0, stream>>>(
        svals, d4b, ego_b, te_b, row_start, csr_tail, A4, d4a, out, ego_b, te_b);
}